// Round 7
// baseline (74.649 us; speedup 1.0000x reference)
//
#include <hip/hip_runtime.h>

// Median filter 1D, k=9, replicate padding, fp32.
// Input [B=8, C=32, L=131072] flattened: 256 rows of 131072.
//
// R7 experiment: NONTEMPORAL LOADS. in+out = 268 MB > 256 MB L3, so both
// streams partially spill (measured: FETCH 67 MB, WRITE 147 MB). Streaming
// the input (no L3 allocation) leaves the whole 134 MB output L3-resident;
// graph replays rewrite the same (dirty) lines -> steady-state HBM write
// traffic ~0, HBM carries only the pure read stream.
//
// Compute: exact median-of-9 via min3/med3/max3 triple decomposition
// (median9 = med3(max3(los), med3(mids), min3(his)); exact by rank-count).
// 8 consecutive outputs/thread share triples: 14 triple-sorts + 8 combines.

typedef float f32x4 __attribute__((ext_vector_type(4)));

__device__ __forceinline__ float min3f(float a, float b, float c) {
    return fminf(fminf(a, b), c);   // fuses to v_min3_f32
}
__device__ __forceinline__ float max3f(float a, float b, float c) {
    return fmaxf(fmaxf(a, b), c);   // fuses to v_max3_f32
}
__device__ __forceinline__ float med3f(float a, float b, float c) {
    return __builtin_amdgcn_fmed3f(a, b, c);
}

constexpr int kL     = 131072;       // row length (power of two)
constexpr int kTotal = 8 * 32 * kL;  // 33,554,432 = 2^25

__global__ __launch_bounds__(256)
void med9_f32_kernel(const float* __restrict__ in, float* __restrict__ out) {
    int base = (blockIdx.x * 256 + threadIdx.x) * 8;  // 8 consecutive outputs
    int col  = base & (kL - 1);
    const float* __restrict__ rin = in + (base - col);

    // v[0..15] = row elements [col-4, col+11]
    float v[16];
    if (col >= 4 && col + 12 <= kL) {
        // Nontemporal: stream input past the caches, keep L3 for the output.
        f32x4 a = __builtin_nontemporal_load(
                      reinterpret_cast<const f32x4*>(rin + col - 4));
        f32x4 b = __builtin_nontemporal_load(
                      reinterpret_cast<const f32x4*>(rin + col));
        f32x4 c = __builtin_nontemporal_load(
                      reinterpret_cast<const f32x4*>(rin + col + 4));
        f32x4 d = __builtin_nontemporal_load(
                      reinterpret_cast<const f32x4*>(rin + col + 8));
        v[0]  = a.x; v[1]  = a.y; v[2]  = a.z; v[3]  = a.w;
        v[4]  = b.x; v[5]  = b.y; v[6]  = b.z; v[7]  = b.w;
        v[8]  = c.x; v[9]  = c.y; v[10] = c.z; v[11] = c.w;
        v[12] = d.x; v[13] = d.y; v[14] = d.z; v[15] = d.w;
    } else {
        // Row edge: replicate-pad via clamped scalar loads (2 threads/row).
#pragma unroll
        for (int j = 0; j < 16; ++j) {
            int idx = col - 4 + j;
            idx = idx < 0 ? 0 : (idx > kL - 1 ? kL - 1 : idx);
            v[j] = rin[idx];
        }
    }

    // Sort the 14 triples v[j..j+2], j = 0..13.
    float lo[14], mi[14], hi[14];
#pragma unroll
    for (int j = 0; j < 14; ++j) {
        lo[j] = min3f(v[j], v[j + 1], v[j + 2]);
        mi[j] = med3f(v[j], v[j + 1], v[j + 2]);
        hi[j] = max3f(v[j], v[j + 1], v[j + 2]);
    }

    // Output t (window v[t..t+8]) = med3 of combined stats of triples t,t+3,t+6.
    float r[8];
#pragma unroll
    for (int t = 0; t < 8; ++t) {
        float P = max3f(lo[t], lo[t + 3], lo[t + 6]);
        float Q = med3f(mi[t], mi[t + 3], mi[t + 6]);
        float R = min3f(hi[t], hi[t + 3], hi[t + 6]);
        r[t] = med3f(P, Q, R);
    }

    f32x4 r0 = { r[0], r[1], r[2], r[3] };
    f32x4 r1 = { r[4], r[5], r[6], r[7] };
    *reinterpret_cast<f32x4*>(out + base)     = r0;
    *reinterpret_cast<f32x4*>(out + base + 4) = r1;
}

extern "C" void kernel_launch(void* const* d_in, const int* in_sizes, int n_in,
                              void* d_out, int out_size, void* d_ws, size_t ws_size,
                              hipStream_t stream) {
    const float* x = (const float*)d_in[0];
    // d_in[1] is kernel_size (==9); hardcoded (host can't read device memory
    // during graph capture).
    float* out = (float*)d_out;

    int grid = kTotal / (256 * 8);  // 16,384 blocks
    med9_f32_kernel<<<grid, 256, 0, stream>>>(x, out);
}

// Round 8
// 44.759 us; speedup vs baseline: 1.6678x; 1.6678x over previous
//
#include <hip/hip_runtime.h>

// Median filter 1D, k=9, replicate padding, fp32.
// Input [B=8, C=32, L=131072] flattened: 256 rows of 131072.
//
// FINAL (= R5, best measured: 44.7 us, within ~5% of the 6.3 TB/s mixed
// read+write HBM roofline for 268 MB of logical traffic).
//
// Findings log:
//  - 19-CE Paeth network (R0): 47.3 us, VALU ~25% busy.
//  - med3/min3/max3 triple decomposition (exact by rank-counting): VALU ops
//    ~9/output, VALUBusy ~12%. Kernel is memory-floor-bound, not VALU-bound.
//  - Structure-insensitive 44.7-46.2 us across: strided 2x ILP (R4),
//    consecutive-8 (R5), chunked 4-way MLP lane-dense (R6).
//  - Nontemporal STORE (R3): regressed (loses L2 write aggregation).
//  - Nontemporal LOAD (R7): 74.6 us — bypasses read caches entirely, kills
//    both L3 residency (~67 MB/replay saved) and halo reuse. Default cache
//    policy is optimal on gfx950 for this access pattern.
//
// Compute: median9(w) = med3( max3(lo_t,lo_t+3,lo_t+6),
//                             med3(mi_t,mi_t+3,mi_t+6),
//                             min3(hi_t,hi_t+3,hi_t+6) )
// where (lo,mi,hi)[j] sort triple v[j..j+2]. Exact (rank-count proof), and
// min/max/med preserve the reference's sort-based lower-median semantics.
// 8 consecutive outputs/thread share triples: 14 triple-sorts + 8 combines
// = 74 VOP3 ops per 8 outputs, depth 3.

typedef float f32x4 __attribute__((ext_vector_type(4)));

__device__ __forceinline__ float min3f(float a, float b, float c) {
    return fminf(fminf(a, b), c);   // fuses to v_min3_f32
}
__device__ __forceinline__ float max3f(float a, float b, float c) {
    return fmaxf(fmaxf(a, b), c);   // fuses to v_max3_f32
}
__device__ __forceinline__ float med3f(float a, float b, float c) {
    return __builtin_amdgcn_fmed3f(a, b, c);
}

constexpr int kL     = 131072;       // row length (power of two)
constexpr int kTotal = 8 * 32 * kL;  // 33,554,432 = 2^25

__global__ __launch_bounds__(256)
void med9_f32_kernel(const float* __restrict__ in, float* __restrict__ out) {
    int base = (blockIdx.x * 256 + threadIdx.x) * 8;  // 8 consecutive outputs
    int col  = base & (kL - 1);
    const float* __restrict__ rin = in + (base - col);

    // v[0..15] = row elements [col-4, col+11]
    float v[16];
    if (col >= 4 && col + 12 <= kL) {
        f32x4 a = *reinterpret_cast<const f32x4*>(rin + col - 4);
        f32x4 b = *reinterpret_cast<const f32x4*>(rin + col);
        f32x4 c = *reinterpret_cast<const f32x4*>(rin + col + 4);
        f32x4 d = *reinterpret_cast<const f32x4*>(rin + col + 8);
        v[0]  = a.x; v[1]  = a.y; v[2]  = a.z; v[3]  = a.w;
        v[4]  = b.x; v[5]  = b.y; v[6]  = b.z; v[7]  = b.w;
        v[8]  = c.x; v[9]  = c.y; v[10] = c.z; v[11] = c.w;
        v[12] = d.x; v[13] = d.y; v[14] = d.z; v[15] = d.w;
    } else {
        // Row edge: replicate-pad via clamped scalar loads (2 threads/row).
#pragma unroll
        for (int j = 0; j < 16; ++j) {
            int idx = col - 4 + j;
            idx = idx < 0 ? 0 : (idx > kL - 1 ? kL - 1 : idx);
            v[j] = rin[idx];
        }
    }

    // Sort the 14 triples v[j..j+2], j = 0..13.
    float lo[14], mi[14], hi[14];
#pragma unroll
    for (int j = 0; j < 14; ++j) {
        lo[j] = min3f(v[j], v[j + 1], v[j + 2]);
        mi[j] = med3f(v[j], v[j + 1], v[j + 2]);
        hi[j] = max3f(v[j], v[j + 1], v[j + 2]);
    }

    // Output t (window v[t..t+8]) = med3 of combined stats of triples t,t+3,t+6.
    float r[8];
#pragma unroll
    for (int t = 0; t < 8; ++t) {
        float P = max3f(lo[t], lo[t + 3], lo[t + 6]);
        float Q = med3f(mi[t], mi[t + 3], mi[t + 6]);
        float R = min3f(hi[t], hi[t + 3], hi[t + 6]);
        r[t] = med3f(P, Q, R);
    }

    f32x4 r0 = { r[0], r[1], r[2], r[3] };
    f32x4 r1 = { r[4], r[5], r[6], r[7] };
    *reinterpret_cast<f32x4*>(out + base)     = r0;
    *reinterpret_cast<f32x4*>(out + base + 4) = r1;
}

extern "C" void kernel_launch(void* const* d_in, const int* in_sizes, int n_in,
                              void* d_out, int out_size, void* d_ws, size_t ws_size,
                              hipStream_t stream) {
    const float* x = (const float*)d_in[0];
    // d_in[1] is kernel_size (==9); hardcoded (host can't read device memory
    // during graph capture).
    float* out = (float*)d_out;

    int grid = kTotal / (256 * 8);  // 16,384 blocks
    med9_f32_kernel<<<grid, 256, 0, stream>>>(x, out);
}